// Round 8
// baseline (1761.358 us; speedup 1.0000x reference)
//
#include <hip/hip_runtime.h>

#define B_ 64
#define T_ 2048
#define I_ 128
#define H_ 128
#define CHUNK 128
#define NCHUNK (T_ / CHUNK)

typedef _Float16 half2v __attribute__((ext_vector_type(2)));

__device__ __forceinline__ float fdot2(unsigned h, unsigned w, float acc) {
#if __has_builtin(__builtin_amdgcn_fdot2)
    return __builtin_amdgcn_fdot2(__builtin_bit_cast(half2v, h),
                                  __builtin_bit_cast(half2v, w), acc, false);
#else
    half2v a = __builtin_bit_cast(half2v, h);
    half2v b = __builtin_bit_cast(half2v, w);
    acc = fmaf((float)a.x, (float)b.x, acc);
    return fmaf((float)a.y, (float)b.y, acc);
#endif
}

__device__ __forceinline__ unsigned pkh(float a, float b) {
    half2v v; v.x = (_Float16)a; v.y = (_Float16)b;
    return __builtin_bit_cast(unsigned, v);
}

// ---------------- Phase 1: xp = x @ W_xh^T + b_xh ----------------
__global__ __launch_bounds__(256) void xp_gemm(
    const float* __restrict__ x, const float* __restrict__ Wxh,
    const float* __restrict__ bxh, float* __restrict__ xp)
{
    __shared__ float ws[H_ * I_];   // 64 KB, row-major [h][i]
    const int tid = threadIdx.x;
    {
        const float4* src = (const float4*)Wxh;
        float4* dst = (float4*)ws;
        #pragma unroll
        for (int i = 0; i < (H_ * I_ / 4) / 256; ++i)
            dst[tid + i * 256] = src[tid + i * 256];
    }
    __syncthreads();

    const int r0 = (tid >> 4) * 8;
    const int c0 = (tid & 15) * 8;
    const float* xb = x + ((size_t)blockIdx.x * 128 + r0) * I_;
    const float* wb = ws + c0 * I_;

    float acc[8][8];
    #pragma unroll
    for (int i = 0; i < 8; ++i)
        #pragma unroll
        for (int j = 0; j < 8; ++j) acc[i][j] = 0.f;

    float4 xa[8], wa[8], xn[8], wn[8];
    #pragma unroll
    for (int i = 0; i < 8; ++i) xa[i] = *(const float4*)(xb + i * I_);
    #pragma unroll
    for (int j = 0; j < 8; ++j) wa[j] = *(const float4*)(wb + j * I_);

    for (int k4 = 0; k4 < 32; k4 += 2) {
        #pragma unroll
        for (int i = 0; i < 8; ++i) xn[i] = *(const float4*)(xb + i * I_ + k4 * 4 + 4);
        #pragma unroll
        for (int j = 0; j < 8; ++j) wn[j] = *(const float4*)(wb + j * I_ + k4 * 4 + 4);
        #pragma unroll
        for (int i = 0; i < 8; ++i)
            #pragma unroll
            for (int j = 0; j < 8; ++j) {
                acc[i][j] = fmaf(xa[i].x, wa[j].x, acc[i][j]);
                acc[i][j] = fmaf(xa[i].y, wa[j].y, acc[i][j]);
                acc[i][j] = fmaf(xa[i].z, wa[j].z, acc[i][j]);
                acc[i][j] = fmaf(xa[i].w, wa[j].w, acc[i][j]);
            }
        if (k4 + 2 < 32) {
            #pragma unroll
            for (int i = 0; i < 8; ++i) xa[i] = *(const float4*)(xb + i * I_ + k4 * 4 + 8);
            #pragma unroll
            for (int j = 0; j < 8; ++j) wa[j] = *(const float4*)(wb + j * I_ + k4 * 4 + 8);
        }
        #pragma unroll
        for (int i = 0; i < 8; ++i)
            #pragma unroll
            for (int j = 0; j < 8; ++j) {
                acc[i][j] = fmaf(xn[i].x, wn[j].x, acc[i][j]);
                acc[i][j] = fmaf(xn[i].y, wn[j].y, acc[i][j]);
                acc[i][j] = fmaf(xn[i].z, wn[j].z, acc[i][j]);
                acc[i][j] = fmaf(xn[i].w, wn[j].w, acc[i][j]);
            }
    }

    const float4 b0 = *(const float4*)(bxh + c0);
    const float4 b1 = *(const float4*)(bxh + c0 + 4);
    float* orow = xp + ((size_t)blockIdx.x * 128 + r0) * H_ + c0;
    #pragma unroll
    for (int i = 0; i < 8; ++i) {
        float4 o0, o1;
        o0.x = acc[i][0] + b0.x; o0.y = acc[i][1] + b0.y;
        o0.z = acc[i][2] + b0.z; o0.w = acc[i][3] + b0.w;
        o1.x = acc[i][4] + b1.x; o1.y = acc[i][5] + b1.y;
        o1.z = acc[i][6] + b1.z; o1.w = acc[i][7] + b1.w;
        *(float4*)(orow + i * H_) = o0;
        *(float4*)(orow + i * H_ + 4) = o1;
    }
}

// Stage one 128-step xp chunk (64 KB) into LDS, 64 lanes x 16 B x 64 iters.
__device__ __forceinline__ void stage_chunk64(const float* __restrict__ g,
                                              float* l, int ln)
{
    #pragma unroll
    for (int i = 0; i < 64; ++i) {
        const int off = i * 256;
        __builtin_amdgcn_global_load_lds(
            (const __attribute__((address_space(1))) unsigned int*)(g + off + ln * 4),
            (__attribute__((address_space(3))) unsigned int*)(l + off),
            16, 0, 0);
    }
}

// ---- macro repetition: weights as NAMED + PINNED scalars ----
#define G16(M) M(0) M(1) M(2) M(3) M(4) M(5) M(6) M(7) \
               M(8) M(9) M(10) M(11) M(12) M(13) M(14) M(15)

#define DECLW(g) unsigned wa##g##_0, wa##g##_1, wa##g##_2, wa##g##_3, \
                          wb##g##_0, wb##g##_1, wb##g##_2, wb##g##_3;
#define LOADW(g) { \
    const float4 xA0 = *(const float4*)(rowA + 8 * g);     \
    const float4 xA1 = *(const float4*)(rowA + 8 * g + 4); \
    wa##g##_0 = pkh(xA0.x, xA0.y); wa##g##_1 = pkh(xA0.z, xA0.w); \
    wa##g##_2 = pkh(xA1.x, xA1.y); wa##g##_3 = pkh(xA1.z, xA1.w); \
    const float4 xB0 = *(const float4*)(rowB + 8 * g);     \
    const float4 xB1 = *(const float4*)(rowB + 8 * g + 4); \
    wb##g##_0 = pkh(xB0.x, xB0.y); wb##g##_1 = pkh(xB0.z, xB0.w); \
    wb##g##_2 = pkh(xB1.x, xB1.y); wb##g##_3 = pkh(xB1.z, xB1.w); }
#define PINW(g) asm("" : "+v"(wa##g##_0), "+v"(wa##g##_1), "+v"(wa##g##_2), "+v"(wa##g##_3), \
                        "+v"(wb##g##_0), "+v"(wb##g##_1), "+v"(wb##g##_2), "+v"(wb##g##_3));

// Read one 16B h chunk then immediately consume it (short live range).
#define STEPG(g) { \
    const uint4 hv = hbp[g]; \
    a00 = fdot2(hv.x, wa##g##_0, a00); a01 = fdot2(hv.y, wa##g##_1, a01); \
    a00 = fdot2(hv.z, wa##g##_2, a00); a01 = fdot2(hv.w, wa##g##_3, a01); \
    a10 = fdot2(hv.x, wb##g##_0, a10); a11 = fdot2(hv.y, wb##g##_1, a11); \
    a10 = fdot2(hv.z, wb##g##_2, a10); a11 = fdot2(hv.w, wb##g##_3, a11); }

// ---------------- Phase 2: scan, ONE WAVE per batch ----------------
// amdgpu_waves_per_eu(1,1): pin codegen occupancy target to 1 wave/EU so the
// VGPR budget is 512, not the default-heuristic 128ish that forced the 128
// weight dwords to spill/reload every step in rounds 4/6/7 (VGPR_Count was
// stuck at 132 regardless of structure -- the diagnostic for this round).
__global__ __launch_bounds__(64)
__attribute__((amdgpu_waves_per_eu(1, 1)))
void rnn_scan(
    const float* __restrict__ Whh, const float* __restrict__ bhh,
    float* __restrict__ seq /* xp in, h_seq out */, float* __restrict__ hlast)
{
    __shared__ float xpl[2][CHUNK * H_];   // 128 KB
    __shared__ unsigned hpk[2][64];        // packed f16 h, double buffered

    const int l = threadIdx.x;             // 0..63
    const int b = blockIdx.x;
    const int j0 = 2 * l;

    const float* rowA = Whh + (size_t)j0 * H_;
    const float* rowB = Whh + (size_t)(j0 + 1) * H_;

    G16(DECLW)
    G16(LOADW)
    G16(PINW)

    const float2 bj = *(const float2*)&bhh[j0];
    const float bj0 = bj.x, bj1 = bj.y;
    hpk[0][l] = 0u;
    hpk[1][l] = 0u;

    float* xp = seq + (size_t)b * T_ * H_;
    stage_chunk64(xp, &xpl[0][0], l);      // prologue: chunk 0

    float h0 = 0.f, h1 = 0.f;
    int tg = 0;
    for (int c = 0; c < NCHUNK; ++c) {
        asm volatile("s_waitcnt vmcnt(0)" ::: "memory");   // chunk-c LDS data ready
        if (c + 1 < NCHUNK)
            stage_chunk64(xp + (size_t)(c + 1) * CHUNK * H_, &xpl[(c + 1) & 1][0], l);

        const float* xb = &xpl[c & 1][0];
        float* sq = xp + (size_t)c * CHUNK * H_;

        for (int t = 0; t < CHUNK; ++t, ++tg) {
            const uint4* hbp = (const uint4*)&hpk[tg & 1][0];
            float a00 = bj0, a01 = 0.f, a10 = bj1, a11 = 0.f;
            G16(STEPG)                      // 16 broadcast b128 interleaved with 128 dot2
            const float2 xc = *(const float2*)&xb[t * H_ + j0];
            const float p0 = xc.x + a00 + a01;
            const float p1 = xc.y + a10 + a11;
            // tanh(x) = 1 - 2/(exp2(2x*log2e)+1)
            const float e0 = exp2f(p0 * 2.8853900817779268f);
            const float e1 = exp2f(p1 * 2.8853900817779268f);
            h0 = 1.f - 2.f * __builtin_amdgcn_rcpf(e0 + 1.f);
            h1 = 1.f - 2.f * __builtin_amdgcn_rcpf(e1 + 1.f);
            hpk[(tg & 1) ^ 1][l] = pkh(h0, h1);               // ds_write; same-wave in-order
            *(float2*)&sq[t * H_ + j0] = make_float2(h0, h1); // queued global store
        }
    }
    *(float2*)&hlast[b * H_ + j0] = make_float2(h0, h1);
}

extern "C" void kernel_launch(void* const* d_in, const int* in_sizes, int n_in,
                              void* d_out, int out_size, void* d_ws, size_t ws_size,
                              hipStream_t stream)
{
    const float* x   = (const float*)d_in[0];
    const float* Wxh = (const float*)d_in[1];
    const float* bxh = (const float*)d_in[2];
    const float* Whh = (const float*)d_in[3];
    const float* bhh = (const float*)d_in[4];
    float* out   = (float*)d_out;
    float* hlast = out + (size_t)B_ * T_ * H_;

    xp_gemm<<<(B_ * T_) / 128, 256, 0, stream>>>(x, Wxh, bxh, out);
    rnn_scan<<<B_, 64, 0, stream>>>(Whh, bhh, out, hlast);
}

// Round 9
// 1173.811 us; speedup vs baseline: 1.5005x; 1.5005x over previous
//
#include <hip/hip_runtime.h>

#define B_ 64
#define T_ 2048
#define I_ 128
#define H_ 128
#define CHUNK 128
#define NCHUNK (T_ / CHUNK)

typedef _Float16 f16x8 __attribute__((ext_vector_type(8)));
typedef float    f32x4 __attribute__((ext_vector_type(4)));
typedef int      i32x4 __attribute__((ext_vector_type(4)));

// ---------------- Phase 1: xp = x @ W_xh^T + (b_xh + b_hh) ----------------
// b_hh folded in here so the scan kernel needs no bias at all.
__global__ __launch_bounds__(256) void xp_gemm(
    const float* __restrict__ x, const float* __restrict__ Wxh,
    const float* __restrict__ bxh, const float* __restrict__ bhh,
    float* __restrict__ xp)
{
    __shared__ float ws[H_ * I_];   // 64 KB, row-major [h][i]
    const int tid = threadIdx.x;
    {
        const float4* src = (const float4*)Wxh;
        float4* dst = (float4*)ws;
        #pragma unroll
        for (int i = 0; i < (H_ * I_ / 4) / 256; ++i)
            dst[tid + i * 256] = src[tid + i * 256];
    }
    __syncthreads();

    const int r0 = (tid >> 4) * 8;
    const int c0 = (tid & 15) * 8;
    const float* xb = x + ((size_t)blockIdx.x * 128 + r0) * I_;
    const float* wb = ws + c0 * I_;

    float acc[8][8];
    #pragma unroll
    for (int i = 0; i < 8; ++i)
        #pragma unroll
        for (int j = 0; j < 8; ++j) acc[i][j] = 0.f;

    float4 xa[8], wa[8], xn[8], wn[8];
    #pragma unroll
    for (int i = 0; i < 8; ++i) xa[i] = *(const float4*)(xb + i * I_);
    #pragma unroll
    for (int j = 0; j < 8; ++j) wa[j] = *(const float4*)(wb + j * I_);

    for (int k4 = 0; k4 < 32; k4 += 2) {
        #pragma unroll
        for (int i = 0; i < 8; ++i) xn[i] = *(const float4*)(xb + i * I_ + k4 * 4 + 4);
        #pragma unroll
        for (int j = 0; j < 8; ++j) wn[j] = *(const float4*)(wb + j * I_ + k4 * 4 + 4);
        #pragma unroll
        for (int i = 0; i < 8; ++i)
            #pragma unroll
            for (int j = 0; j < 8; ++j) {
                acc[i][j] = fmaf(xa[i].x, wa[j].x, acc[i][j]);
                acc[i][j] = fmaf(xa[i].y, wa[j].y, acc[i][j]);
                acc[i][j] = fmaf(xa[i].z, wa[j].z, acc[i][j]);
                acc[i][j] = fmaf(xa[i].w, wa[j].w, acc[i][j]);
            }
        if (k4 + 2 < 32) {
            #pragma unroll
            for (int i = 0; i < 8; ++i) xa[i] = *(const float4*)(xb + i * I_ + k4 * 4 + 8);
            #pragma unroll
            for (int j = 0; j < 8; ++j) wa[j] = *(const float4*)(wb + j * I_ + k4 * 4 + 8);
        }
        #pragma unroll
        for (int i = 0; i < 8; ++i)
            #pragma unroll
            for (int j = 0; j < 8; ++j) {
                acc[i][j] = fmaf(xn[i].x, wn[j].x, acc[i][j]);
                acc[i][j] = fmaf(xn[i].y, wn[j].y, acc[i][j]);
                acc[i][j] = fmaf(xn[i].z, wn[j].z, acc[i][j]);
                acc[i][j] = fmaf(xn[i].w, wn[j].w, acc[i][j]);
            }
    }

    const float4 ba0 = *(const float4*)(bxh + c0);
    const float4 ba1 = *(const float4*)(bxh + c0 + 4);
    const float4 bb0 = *(const float4*)(bhh + c0);
    const float4 bb1 = *(const float4*)(bhh + c0 + 4);
    float* orow = xp + ((size_t)blockIdx.x * 128 + r0) * H_ + c0;
    #pragma unroll
    for (int i = 0; i < 8; ++i) {
        float4 o0, o1;
        o0.x = acc[i][0] + ba0.x + bb0.x; o0.y = acc[i][1] + ba0.y + bb0.y;
        o0.z = acc[i][2] + ba0.z + bb0.z; o0.w = acc[i][3] + ba0.w + bb0.w;
        o1.x = acc[i][4] + ba1.x + bb1.x; o1.y = acc[i][5] + ba1.y + bb1.y;
        o1.z = acc[i][6] + ba1.z + bb1.z; o1.w = acc[i][7] + ba1.w + bb1.w;
        *(float4*)(orow + i * H_) = o0;
        *(float4*)(orow + i * H_ + 4) = o1;
    }
}

// Stage one 128-step xp chunk (64 KB) into LDS, 64 lanes x 16 B x 64 iters.
__device__ __forceinline__ void stage_chunk64(const float* __restrict__ g,
                                              float* l, int ln)
{
    #pragma unroll
    for (int i = 0; i < 64; ++i) {
        const int off = i * 256;
        __builtin_amdgcn_global_load_lds(
            (const __attribute__((address_space(1))) unsigned int*)(g + off + ln * 4),
            (__attribute__((address_space(3))) unsigned int*)(l + off),
            16, 0, 0);
    }
}

// ---- 32 B-fragments (q=0..3 k-tiles, n=0..7 col-tiles), stored in AGPRs ----
#define FORALL(M) \
  M(0,0) M(1,0) M(2,0) M(3,0)  M(0,1) M(1,1) M(2,1) M(3,1) \
  M(0,2) M(1,2) M(2,2) M(3,2)  M(0,3) M(1,3) M(2,3) M(3,3) \
  M(0,4) M(1,4) M(2,4) M(3,4)  M(0,5) M(1,5) M(2,5) M(3,5) \
  M(0,6) M(1,6) M(2,6) M(3,6)  M(0,7) M(1,7) M(2,7) M(3,7)

#define DECLB(q,n) i32x4 bf_##q##_##n;
// B[k][col] = Whh[col][k]; lane holds col = n*16 + (l&15), k = q*32 + grp*8 + e
// (8 consecutive k per lane -- the m92/m97 refcheck-verified fragment layout).
#define LOADB(q,n) { \
    const float* wr_ = Whh + (size_t)((n)*16 + c15) * H_ + (q)*32 + grp*8; \
    const float4 u0_ = *(const float4*)wr_; \
    const float4 u1_ = *(const float4*)(wr_ + 4); \
    f16x8 t_; \
    t_[0]=(_Float16)u0_.x; t_[1]=(_Float16)u0_.y; t_[2]=(_Float16)u0_.z; t_[3]=(_Float16)u0_.w; \
    t_[4]=(_Float16)u1_.x; t_[5]=(_Float16)u1_.y; t_[6]=(_Float16)u1_.z; t_[7]=(_Float16)u1_.w; \
    bf_##q##_##n = __builtin_bit_cast(i32x4, t_); }
// Force residency in the ACCUMULATOR file -- the register space rounds 4-8
// proved the allocator leaves untouched for non-MFMA kernels.
#define PINB(q,n) asm volatile("" : "+a"(bf_##q##_##n));

#define FORN(M) M(0) M(1) M(2) M(3) M(4) M(5) M(6) M(7)
// One output col-tile: 4 chained MFMAs over the k-tiles. A = replicated h.
#define TILE(n) \
  f32x4 acc##n = __builtin_amdgcn_mfma_f32_16x16x32_f16(a0, __builtin_bit_cast(f16x8, bf_0_##n), zc, 0, 0, 0); \
  acc##n = __builtin_amdgcn_mfma_f32_16x16x32_f16(a1, __builtin_bit_cast(f16x8, bf_1_##n), acc##n, 0, 0, 0); \
  acc##n = __builtin_amdgcn_mfma_f32_16x16x32_f16(a2, __builtin_bit_cast(f16x8, bf_2_##n), acc##n, 0, 0, 0); \
  acc##n = __builtin_amdgcn_mfma_f32_16x16x32_f16(a3, __builtin_bit_cast(f16x8, bf_3_##n), acc##n, 0, 0, 0);

// ---------------- Phase 2: scan, ONE WAVE per batch, MFMA matvec ----------------
// h_new^T = tanh(xp_t + W_hh @ h): A[16x32] = h-chunk replicated in all 16 rows
// (row-mapping-agnostic), B[32x16] = W^T chunk from AGPRs, D col = lane&15
// (m89-verified), rows replicated -> lane's useful outputs are cols
// grp*32+(l&15) and +16 (tiles 2*grp, 2*grp+1). h round-trips through a 256 B
// f16 LDS buffer (2 b16 writes + 4 broadcast b128 reads). Single wave ->
// in-order DS pipe gives every RAW for free; NO barriers anywhere.
__global__ __launch_bounds__(64) void rnn_scan(
    const float* __restrict__ Whh,
    float* __restrict__ seq /* xp in, h_seq out */, float* __restrict__ hlast)
{
    __shared__ float xpl[2][CHUNK * H_];   // 128 KB
    __shared__ _Float16 hA[H_], hB[H_];    // h ping-pong, 256 B each

    const int l   = threadIdx.x;           // 0..63
    const int b   = blockIdx.x;
    const int c15 = l & 15;
    const int grp = l >> 4;
    const int c0  = grp * 32 + c15;        // my output col in tile 2*grp
    const int c1  = c0 + 16;               // my output col in tile 2*grp+1

    FORALL(DECLB)
    FORALL(LOADB)
    FORALL(PINB)

    hA[2 * l] = (_Float16)0.f;
    hA[2 * l + 1] = (_Float16)0.f;

    const f32x4 zc = {0.f, 0.f, 0.f, 0.f}; // zeroed once, reused as C-in

    float* xp = seq + (size_t)b * T_ * H_;
    stage_chunk64(xp, &xpl[0][0], l);      // prologue: chunk 0

    auto step = [&](const _Float16* hr, _Float16* hw,
                    const float* xrow, float* sqrow) {
        const float xv0 = xrow[c0];                    // ds_read_b32 (xp + biases)
        const float xv1 = xrow[c1];
        const f16x8 a0 = *(const f16x8*)(hr + grp * 8);        // broadcast b128
        const f16x8 a1 = *(const f16x8*)(hr + 32 + grp * 8);
        const f16x8 a2 = *(const f16x8*)(hr + 64 + grp * 8);
        const f16x8 a3 = *(const f16x8*)(hr + 96 + grp * 8);
        FORN(TILE)                                     // 32 MFMA, 8 indep chains
        const float r0 = grp == 0 ? acc0.x : grp == 1 ? acc2.x : grp == 2 ? acc4.x : acc6.x;
        const float r1 = grp == 0 ? acc1.x : grp == 1 ? acc3.x : grp == 2 ? acc5.x : acc7.x;
        const float p0 = r0 + xv0;
        const float p1 = r1 + xv1;
        // tanh(x) = 1 - 2/(exp2(2x*log2e)+1)
        const float e0 = exp2f(p0 * 2.8853900817779268f);
        const float e1 = exp2f(p1 * 2.8853900817779268f);
        const float h0 = 1.f - 2.f * __builtin_amdgcn_rcpf(e0 + 1.f);
        const float h1 = 1.f - 2.f * __builtin_amdgcn_rcpf(e1 + 1.f);
        hw[c0] = (_Float16)h0;                         // ds_write_b16 x2
        hw[c1] = (_Float16)h1;
        const float s0 = (float)hw[2 * l];             // in-order DS: sees all writes
        const float s1 = (float)hw[2 * l + 1];
        *(float2*)(sqrow + 2 * l) = make_float2(s0, s1);  // coalesced, queued
    };

    for (int c = 0; c < NCHUNK; ++c) {
        asm volatile("s_waitcnt vmcnt(0)" ::: "memory");   // chunk-c LDS ready
        if (c + 1 < NCHUNK)
            stage_chunk64(xp + (size_t)(c + 1) * CHUNK * H_, &xpl[(c + 1) & 1][0], l);

        const float* xb = &xpl[c & 1][0];
        float* sq = xp + (size_t)c * CHUNK * H_;

        for (int t = 0; t < CHUNK; t += 2) {
            step(hA, hB, xb + (size_t)t * H_, sq + (size_t)t * H_);
            step(hB, hA, xb + (size_t)(t + 1) * H_, sq + (size_t)(t + 1) * H_);
        }
    }
    // T even -> final h lives in hA
    const float f0 = (float)hA[2 * l];
    const float f1 = (float)hA[2 * l + 1];
    *(float2*)&hlast[b * H_ + 2 * l] = make_float2(f0, f1);
}

extern "C" void kernel_launch(void* const* d_in, const int* in_sizes, int n_in,
                              void* d_out, int out_size, void* d_ws, size_t ws_size,
                              hipStream_t stream)
{
    const float* x   = (const float*)d_in[0];
    const float* Wxh = (const float*)d_in[1];
    const float* bxh = (const float*)d_in[2];
    const float* Whh = (const float*)d_in[3];
    const float* bhh = (const float*)d_in[4];
    float* out   = (float*)d_out;
    float* hlast = out + (size_t)B_ * T_ * H_;

    xp_gemm<<<(B_ * T_) / 128, 256, 0, stream>>>(x, Wxh, bxh, bhh, out);
    rnn_scan<<<B_, 64, 0, stream>>>(Whh, out, hlast);
}